// Round 2
// baseline (717.751 us; speedup 1.0000x reference)
//
#include <hip/hip_runtime.h>
#include <hip/hip_bf16.h>

typedef __bf16 bf16x8 __attribute__((ext_vector_type(8)));
typedef unsigned short u16x8 __attribute__((ext_vector_type(8)));
typedef float f32x4 __attribute__((ext_vector_type(4)));
typedef __hip_bfloat16 hbf;

static constexpr int B = 4, T = 512, D = 1024, N = 16, H = 256;
static constexpr size_t E_ELEMS = (size_t)B * N * T * D;    // 33,554,432
static constexpr size_t ATTN_ELEMS = (size_t)B * N * T * T; // 16,777,216

__device__ __forceinline__ bf16x8 load8(const hbf* p) {
  return *reinterpret_cast<const bf16x8*>(p);
}

__device__ __forceinline__ unsigned short f2bf(float f) {
  union { __hip_bfloat16 h; unsigned short u; } cv;
  cv.h = __float2bfloat16(f);
  return cv.u;
}

// ---------------- fp32 -> bf16 row-major cast (8 elems / thread) -------------
__global__ __launch_bounds__(256) void cast_bf_k(const float* __restrict__ in,
                                                 unsigned short* __restrict__ out,
                                                 int n8) {
  int i = blockIdx.x * 256 + threadIdx.x;
  if (i >= n8) return;
  const float4* p = reinterpret_cast<const float4*>(in) + (size_t)i * 2;
  float4 a = p[0], b = p[1];
  u16x8 v;
  v[0] = f2bf(a.x); v[1] = f2bf(a.y); v[2] = f2bf(a.z); v[3] = f2bf(a.w);
  v[4] = f2bf(b.x); v[5] = f2bf(b.y); v[6] = f2bf(b.z); v[7] = f2bf(b.w);
  reinterpret_cast<u16x8*>(out)[i] = v;
}

// ------------- batched transpose+cast: in[z][r][c] fp32 -> out[z][c][r] bf16 -
__global__ void transpose_cast_k(const float* __restrict__ in,
                                 unsigned short* __restrict__ out, int R, int C) {
  __shared__ unsigned short tile[32][33];
  int z = blockIdx.z;
  int c0 = blockIdx.x * 32, r0 = blockIdx.y * 32;
  const float* inz = in + (size_t)z * R * C;
  unsigned short* outz = out + (size_t)z * R * C;
  int tx = threadIdx.x, ty = threadIdx.y;
  for (int i = ty; i < 32; i += 8)
    tile[i][tx] = f2bf(inz[(size_t)(r0 + i) * C + (c0 + tx)]);
  __syncthreads();
  for (int i = ty; i < 32; i += 8)
    outz[(size_t)(c0 + i) * R + (r0 + tx)] = tile[tx][i];
}

// ---------------- stage A: wq[bn][t][h] = sum_d x[b][t][d] * w[n][d][h] ------
// A = x_bf [T][D] (k contiguous), B via wT[n][h][d] (k contiguous)
// wave computes 64x16 C tile (4 m-subtiles); output bf16
__global__ __launch_bounds__(256) void gemm_wq_k(const hbf* __restrict__ xb,
                                                 const hbf* __restrict__ wT,
                                                 hbf* __restrict__ wq) {
  int wave = threadIdx.x >> 6, lane = threadIdx.x & 63;
  int gwave = blockIdx.x * 4 + wave;      // 8192 waves
  int bn = gwave >> 7;                    // 128 waves per (b,n)
  int local = gwave & 127;
  int mt = local >> 4;                    // 0..7  (64-row block)
  int nt = local & 15;                    // 0..15 (16-col block)
  int b = bn >> 4, n = bn & 15;
  const hbf* A = xb + (size_t)b * T * D;
  const hbf* Bt = wT + (size_t)n * H * D;
  hbf* C = wq + (size_t)bn * T * H;
  int col = lane & 15, quad = lane >> 4;
  int m0 = mt * 64;
  int h = nt * 16 + col;
  f32x4 acc[4] = {};
  const hbf* Brow = Bt + (size_t)h * D;
  for (int k0 = 0; k0 < D; k0 += 32) {
    int k = k0 + quad * 8;
    bf16x8 bfrag = load8(Brow + k);
#pragma unroll
    for (int s = 0; s < 4; ++s) {
      bf16x8 afrag = load8(A + (size_t)(m0 + s * 16 + col) * D + k);
      acc[s] = __builtin_amdgcn_mfma_f32_16x16x32_bf16(afrag, bfrag, acc[s], 0, 0, 0);
    }
  }
#pragma unroll
  for (int s = 0; s < 4; ++s)
#pragma unroll
    for (int r = 0; r < 4; ++r)
      C[(size_t)(m0 + s * 16 + quad * 4 + r) * H + h] = __float2bfloat16(acc[s][r]);
}

// ------- stage B: S = wq_bn @ wq_bn^T (16 rows/block), softmax,
//         write attn fp32 to d_out (output 1) and bf16 to ws (stage-C operand)
__global__ __launch_bounds__(256) void attn_k(const hbf* __restrict__ wq,
                                              float* __restrict__ attn_f,
                                              hbf* __restrict__ attn_b) {
  __shared__ float S[16][516];  // +4 pad
  int blk = blockIdx.x;        // 2048 blocks
  int bn = blk >> 5;
  int mt = blk & 31;
  const hbf* Wq = wq + (size_t)bn * T * H;
  int wave = threadIdx.x >> 6, lane = threadIdx.x & 63;
  int col = lane & 15, quad = lane >> 4;
  int m0 = mt * 16;
  f32x4 acc[8] = {};
  for (int k0 = 0; k0 < H; k0 += 32) {
    int k = k0 + quad * 8;
    bf16x8 afrag = load8(Wq + (size_t)(m0 + col) * H + k);
#pragma unroll
    for (int t = 0; t < 8; ++t) {
      int jrow = wave * 128 + t * 16 + col;       // B col index = wq row
      bf16x8 bfrag = load8(Wq + (size_t)jrow * H + k);
      acc[t] = __builtin_amdgcn_mfma_f32_16x16x32_bf16(afrag, bfrag, acc[t], 0, 0, 0);
    }
  }
#pragma unroll
  for (int t = 0; t < 8; ++t)
#pragma unroll
    for (int r = 0; r < 4; ++r)
      S[quad * 4 + r][wave * 128 + t * 16 + col] = acc[t][r];
  __syncthreads();
  // softmax: wave w handles rows 4w..4w+3 (512 values each, 8/lane)
  for (int rr = 0; rr < 4; ++rr) {
    int row = wave * 4 + rr;
    float v[8];
    float mx = -1e30f;
#pragma unroll
    for (int i = 0; i < 8; ++i) { v[i] = S[row][lane + i * 64]; mx = fmaxf(mx, v[i]); }
#pragma unroll
    for (int off = 32; off > 0; off >>= 1) mx = fmaxf(mx, __shfl_xor(mx, off));
    float sum = 0.f;
#pragma unroll
    for (int i = 0; i < 8; ++i) { v[i] = __expf(v[i] - mx); sum += v[i]; }
#pragma unroll
    for (int off = 32; off > 0; off >>= 1) sum += __shfl_xor(sum, off);
    float inv = 1.0f / sum;
    size_t base = ((size_t)bn * T + m0 + row) * T;
    float* dst = attn_f + base;
    hbf* dstb = attn_b + base;
#pragma unroll
    for (int i = 0; i < 8; ++i) {
      float p = v[i] * inv;
      dst[lane + i * 64] = p;
      dstb[lane + i * 64] = __float2bfloat16(p);
    }
  }
}

// ------- stage C: e[bn][s][d] = sum_t attn[bn][s][t] * x[b][t][d] ------------
// A = attn_b [T][T] bf16 (k contiguous), B via xT[b][d][t] bf16 (k contiguous)
__global__ __launch_bounds__(256) void gemm_out_k(const hbf* __restrict__ attn,
                                                  const hbf* __restrict__ xT,
                                                  float* __restrict__ eout) {
  int wave = threadIdx.x >> 6, lane = threadIdx.x & 63;
  int gwave = blockIdx.x * 4 + wave;      // 32768 waves
  int bn = gwave >> 9;                    // 512 waves per (b,n)
  int local = gwave & 511;
  int mt = local >> 6;                    // 0..7  (64-row block)
  int nt = local & 63;                    // 0..63 (16-col block)
  int b = bn >> 4;
  const hbf* A = attn + (size_t)bn * T * T;
  const hbf* Bt = xT + (size_t)b * D * T;
  float* C = eout + (size_t)bn * T * D;
  int col = lane & 15, quad = lane >> 4;
  int m0 = mt * 64;
  int d = nt * 16 + col;
  f32x4 acc[4] = {};
  const hbf* Brow = Bt + (size_t)d * T;
  for (int k0 = 0; k0 < T; k0 += 32) {
    int k = k0 + quad * 8;
    bf16x8 bfrag = load8(Brow + k);
#pragma unroll
    for (int s = 0; s < 4; ++s) {
      bf16x8 afrag = load8(A + (size_t)(m0 + s * 16 + col) * T + k);
      acc[s] = __builtin_amdgcn_mfma_f32_16x16x32_bf16(afrag, bfrag, acc[s], 0, 0, 0);
    }
  }
#pragma unroll
  for (int s = 0; s < 4; ++s)
#pragma unroll
    for (int r = 0; r < 4; ++r)
      C[(size_t)(m0 + s * 16 + quad * 4 + r) * D + d] = acc[s][r];
}

extern "C" void kernel_launch(void* const* d_in, const int* in_sizes, int n_in,
                              void* d_out, int out_size, void* d_ws, size_t ws_size,
                              hipStream_t stream) {
  const float* x = (const float*)d_in[0];     // [B,T,D] fp32
  const float* w_qs = (const float*)d_in[1];  // [N,D,H] fp32 (w_ks unused per source bug)
  float* e_out = (float*)d_out;               // [B,N,T,D] fp32
  float* attn_out = e_out + E_ELEMS;          // [B,N,T,T] fp32

  char* ws = (char*)d_ws;
  hbf* x_bf = (hbf*)ws;                          // [B,T,D]   4 MB
  hbf* xT   = (hbf*)(ws + (4u << 20));           // [B,D,T]   4 MB
  hbf* wT   = (hbf*)(ws + (8u << 20));           // [N,H,D]   8 MB
  hbf* wq   = (hbf*)(ws + (16u << 20));          // [B*N,T,H] 16 MB
  hbf* attn_b = (hbf*)(ws + (32u << 20));        // [B*N,T,T] 32 MB

  dim3 tb(32, 8);
  cast_bf_k<<<1024, 256, 0, stream>>>(x, (unsigned short*)x_bf, (B * T * D) / 8);
  transpose_cast_k<<<dim3(H / 32, D / 32, N), tb, 0, stream>>>(
      w_qs, (unsigned short*)wT, D, H);
  transpose_cast_k<<<dim3(D / 32, T / 32, B), tb, 0, stream>>>(
      x, (unsigned short*)xT, T, D);
  gemm_wq_k<<<2048, 256, 0, stream>>>(x_bf, wT, wq);
  attn_k<<<2048, 256, 0, stream>>>(wq, attn_out, attn_b);
  gemm_out_k<<<8192, 256, 0, stream>>>(attn_b, xT, e_out);
}

// Round 3
// 365.200 us; speedup vs baseline: 1.9654x; 1.9654x over previous
//
#include <hip/hip_runtime.h>
#include <hip/hip_bf16.h>

typedef __bf16 bf16x8 __attribute__((ext_vector_type(8)));
typedef unsigned short u16x8 __attribute__((ext_vector_type(8)));
typedef float f32x4 __attribute__((ext_vector_type(4)));
typedef __hip_bfloat16 hbf;

static constexpr int B = 4, T = 512, D = 1024, N = 16, H = 256;
static constexpr size_t E_ELEMS = (size_t)B * N * T * D;    // 33,554,432
static constexpr size_t ATTN_ELEMS = (size_t)B * N * T * T; // 16,777,216

__device__ __forceinline__ bf16x8 load8(const hbf* p) {
  return *reinterpret_cast<const bf16x8*>(p);
}

__device__ __forceinline__ unsigned short f2bf(float f) {
  union { __hip_bfloat16 h; unsigned short u; } cv;
  cv.h = __float2bfloat16(f);
  return cv.u;
}

// async global->LDS, 16B per lane; lds dest must be waveBase + lane*16
__device__ __forceinline__ void gload16(const hbf* g, hbf* l) {
  __builtin_amdgcn_global_load_lds(
      (const __attribute__((address_space(1))) void*)g,
      (__attribute__((address_space(3))) void*)l, 16, 0, 0);
}

// ---------------- fp32 -> bf16 row-major cast (8 elems / thread) -------------
__global__ __launch_bounds__(256) void cast_bf_k(const float* __restrict__ in,
                                                 unsigned short* __restrict__ out,
                                                 int n8) {
  int i = blockIdx.x * 256 + threadIdx.x;
  if (i >= n8) return;
  const float4* p = reinterpret_cast<const float4*>(in) + (size_t)i * 2;
  float4 a = p[0], b = p[1];
  u16x8 v;
  v[0] = f2bf(a.x); v[1] = f2bf(a.y); v[2] = f2bf(a.z); v[3] = f2bf(a.w);
  v[4] = f2bf(b.x); v[5] = f2bf(b.y); v[6] = f2bf(b.z); v[7] = f2bf(b.w);
  reinterpret_cast<u16x8*>(out)[i] = v;
}

// ------------- batched transpose+cast: in[z][r][c] fp32 -> out[z][c][r] bf16 -
__global__ void transpose_cast_k(const float* __restrict__ in,
                                 unsigned short* __restrict__ out, int R, int C) {
  __shared__ unsigned short tile[32][33];
  int z = blockIdx.z;
  int c0 = blockIdx.x * 32, r0 = blockIdx.y * 32;
  const float* inz = in + (size_t)z * R * C;
  unsigned short* outz = out + (size_t)z * R * C;
  int tx = threadIdx.x, ty = threadIdx.y;
  for (int i = ty; i < 32; i += 8)
    tile[i][tx] = f2bf(inz[(size_t)(r0 + i) * C + (c0 + tx)]);
  __syncthreads();
  for (int i = ty; i < 32; i += 8)
    outz[(size_t)(c0 + i) * R + (r0 + tx)] = tile[tx][i];
}

// =========== stage A: wq[b][n][t][h] = sum_d x[b][t][d] * w[n][d][h] =========
// 128x128x(BK=32) LDS-tiled; A = x_bf[b] [512][1024]; B = wT flattened
// [4096][1024] (row j = n*256+h, k-contiguous). 512 blocks.
__global__ __launch_bounds__(256) void gemm_wq_tiled(const hbf* __restrict__ xb,
                                                     const hbf* __restrict__ wT,
                                                     hbf* __restrict__ wq) {
  __shared__ __align__(16) hbf As[128 * 32];
  __shared__ __align__(16) hbf Bs[128 * 32];
  int idx = blockIdx.x;                 // b*128 + mt*32 + jt
  int b = idx >> 7, mt = (idx >> 5) & 3, jt = idx & 31;
  const hbf* A = xb + (size_t)b * T * D + (size_t)mt * 128 * D;
  const hbf* Bp = wT + (size_t)jt * 128 * D;
  int tid = threadIdx.x, wave = tid >> 6, lane = tid & 63;
  int col = lane & 15, quad = lane >> 4;
  int wm = wave & 1, wn = wave >> 1;
  const hbf* stG = (wave < 2) ? A : Bp;  // waves 0,1 stage A; 2,3 stage B
  hbf* stL = (wave < 2) ? As : Bs;
  int ibase = (wave & 1) * 4;            // 4 issues x 64 slots each
  f32x4 acc[4][4] = {};
  for (int k0 = 0; k0 < D; k0 += 32) {
    __syncthreads();
#pragma unroll
    for (int j = 0; j < 4; ++j) {
      int slot = (ibase + j) * 64 + lane;
      int row = slot >> 2, kc = slot & 3;
      gload16(stG + (size_t)row * D + k0 + kc * 8, stL + slot * 8);
    }
    __syncthreads();
    bf16x8 a[4], bb[4];
#pragma unroll
    for (int s = 0; s < 4; ++s)
      a[s] = load8(As + (wm * 64 + s * 16 + col) * 32 + quad * 8);
#pragma unroll
    for (int t = 0; t < 4; ++t)
      bb[t] = load8(Bs + (wn * 64 + t * 16 + col) * 32 + quad * 8);
#pragma unroll
    for (int s = 0; s < 4; ++s)
#pragma unroll
      for (int t = 0; t < 4; ++t)
        acc[s][t] = __builtin_amdgcn_mfma_f32_16x16x32_bf16(a[s], bb[t], acc[s][t], 0, 0, 0);
  }
  hbf* wqb = wq + (size_t)b * 16 * T * H;
#pragma unroll
  for (int s = 0; s < 4; ++s) {
    int row = mt * 128 + wm * 64 + s * 16 + quad * 4;
#pragma unroll
    for (int t = 0; t < 4; ++t) {
      int j = jt * 128 + wn * 64 + t * 16 + col;
      int n = j >> 8, h = j & 255;
      hbf* dst = wqb + (size_t)n * T * H + (size_t)row * H + h;
#pragma unroll
      for (int r = 0; r < 4; ++r)
        dst[(size_t)r * H] = __float2bfloat16(acc[s][t][r]);
    }
  }
}

// ------- stage B: S = wq_bn @ wq_bn^T (16 rows/block), softmax,
//         write attn fp32 to d_out (output 1) and bf16 to ws (stage-C operand)
__global__ __launch_bounds__(256) void attn_k(const hbf* __restrict__ wq,
                                              float* __restrict__ attn_f,
                                              hbf* __restrict__ attn_b) {
  __shared__ float S[16][516];  // +4 pad
  int blk = blockIdx.x;        // 2048 blocks
  int bn = blk >> 5;
  int mt = blk & 31;
  const hbf* Wq = wq + (size_t)bn * T * H;
  int wave = threadIdx.x >> 6, lane = threadIdx.x & 63;
  int col = lane & 15, quad = lane >> 4;
  int m0 = mt * 16;
  f32x4 acc[8] = {};
  for (int k0 = 0; k0 < H; k0 += 32) {
    int k = k0 + quad * 8;
    bf16x8 afrag = load8(Wq + (size_t)(m0 + col) * H + k);
#pragma unroll
    for (int t = 0; t < 8; ++t) {
      int jrow = wave * 128 + t * 16 + col;
      bf16x8 bfrag = load8(Wq + (size_t)jrow * H + k);
      acc[t] = __builtin_amdgcn_mfma_f32_16x16x32_bf16(afrag, bfrag, acc[t], 0, 0, 0);
    }
  }
#pragma unroll
  for (int t = 0; t < 8; ++t)
#pragma unroll
    for (int r = 0; r < 4; ++r)
      S[quad * 4 + r][wave * 128 + t * 16 + col] = acc[t][r];
  __syncthreads();
  for (int rr = 0; rr < 4; ++rr) {
    int row = wave * 4 + rr;
    float v[8];
    float mx = -1e30f;
#pragma unroll
    for (int i = 0; i < 8; ++i) { v[i] = S[row][lane + i * 64]; mx = fmaxf(mx, v[i]); }
#pragma unroll
    for (int off = 32; off > 0; off >>= 1) mx = fmaxf(mx, __shfl_xor(mx, off));
    float sum = 0.f;
#pragma unroll
    for (int i = 0; i < 8; ++i) { v[i] = __expf(v[i] - mx); sum += v[i]; }
#pragma unroll
    for (int off = 32; off > 0; off >>= 1) sum += __shfl_xor(sum, off);
    float inv = 1.0f / sum;
    size_t base = ((size_t)bn * T + m0 + row) * T;
    float* dst = attn_f + base;
    hbf* dstb = attn_b + base;
#pragma unroll
    for (int i = 0; i < 8; ++i) {
      float p = v[i] * inv;
      dst[lane + i * 64] = p;
      dstb[lane + i * 64] = __float2bfloat16(p);
    }
  }
}

// =========== stage C: e[bn][s][d] = sum_t attn[bn][s][t] * x[b][t][d] ========
// 128x128x(BK=32) LDS-tiled; A = attn_b[bn] [512][512]; B = xT[b] [1024][512]
// (k-contiguous). 2048 blocks. fp32 output.
__global__ __launch_bounds__(256) void gemm_out_tiled(const hbf* __restrict__ attn,
                                                      const hbf* __restrict__ xT,
                                                      float* __restrict__ eout) {
  __shared__ __align__(16) hbf As[128 * 32];
  __shared__ __align__(16) hbf Bs[128 * 32];
  int idx = blockIdx.x;                 // bn*32 + mt*8 + nt
  int bn = idx >> 5, mt = (idx >> 3) & 3, nt = idx & 7;
  int b = bn >> 4;
  const hbf* A = attn + (size_t)bn * T * T + (size_t)mt * 128 * T;
  const hbf* Bp = xT + (size_t)b * D * T + (size_t)nt * 128 * T;
  float* C = eout + (size_t)bn * T * D;
  int tid = threadIdx.x, wave = tid >> 6, lane = tid & 63;
  int col = lane & 15, quad = lane >> 4;
  int wm = wave & 1, wn = wave >> 1;
  const hbf* stG = (wave < 2) ? A : Bp;
  hbf* stL = (wave < 2) ? As : Bs;
  int ibase = (wave & 1) * 4;
  f32x4 acc[4][4] = {};
  for (int k0 = 0; k0 < T; k0 += 32) {
    __syncthreads();
#pragma unroll
    for (int j = 0; j < 4; ++j) {
      int slot = (ibase + j) * 64 + lane;
      int row = slot >> 2, kc = slot & 3;
      gload16(stG + (size_t)row * T + k0 + kc * 8, stL + slot * 8);
    }
    __syncthreads();
    bf16x8 a[4], bb[4];
#pragma unroll
    for (int s = 0; s < 4; ++s)
      a[s] = load8(As + (wm * 64 + s * 16 + col) * 32 + quad * 8);
#pragma unroll
    for (int t = 0; t < 4; ++t)
      bb[t] = load8(Bs + (wn * 64 + t * 16 + col) * 32 + quad * 8);
#pragma unroll
    for (int s = 0; s < 4; ++s)
#pragma unroll
      for (int t = 0; t < 4; ++t)
        acc[s][t] = __builtin_amdgcn_mfma_f32_16x16x32_bf16(a[s], bb[t], acc[s][t], 0, 0, 0);
  }
#pragma unroll
  for (int s = 0; s < 4; ++s) {
    int row = mt * 128 + wm * 64 + s * 16 + quad * 4;
#pragma unroll
    for (int t = 0; t < 4; ++t) {
      int d = nt * 128 + wn * 64 + t * 16 + col;
      float* dst = C + (size_t)row * D + d;
#pragma unroll
      for (int r = 0; r < 4; ++r)
        dst[(size_t)r * D] = acc[s][t][r];
    }
  }
}

extern "C" void kernel_launch(void* const* d_in, const int* in_sizes, int n_in,
                              void* d_out, int out_size, void* d_ws, size_t ws_size,
                              hipStream_t stream) {
  const float* x = (const float*)d_in[0];     // [B,T,D] fp32
  const float* w_qs = (const float*)d_in[1];  // [N,D,H] fp32 (w_ks unused per source bug)
  float* e_out = (float*)d_out;               // [B,N,T,D] fp32
  float* attn_out = e_out + E_ELEMS;          // [B,N,T,T] fp32

  char* ws = (char*)d_ws;
  hbf* x_bf = (hbf*)ws;                          // [B,T,D]   4 MB
  hbf* xT   = (hbf*)(ws + (4u << 20));           // [B,D,T]   4 MB
  hbf* wT   = (hbf*)(ws + (8u << 20));           // [N,H,D]   8 MB
  hbf* wq   = (hbf*)(ws + (16u << 20));          // [B*N,T,H] 16 MB
  hbf* attn_b = (hbf*)(ws + (32u << 20));        // [B*N,T,T] 32 MB

  dim3 tb(32, 8);
  cast_bf_k<<<1024, 256, 0, stream>>>(x, (unsigned short*)x_bf, (B * T * D) / 8);
  transpose_cast_k<<<dim3(H / 32, D / 32, N), tb, 0, stream>>>(
      w_qs, (unsigned short*)wT, D, H);
  transpose_cast_k<<<dim3(D / 32, T / 32, B), tb, 0, stream>>>(
      x, (unsigned short*)xT, T, D);
  gemm_wq_tiled<<<512, 256, 0, stream>>>(x_bf, wT, wq);
  attn_k<<<2048, 256, 0, stream>>>(wq, attn_out, attn_b);
  gemm_out_tiled<<<2048, 256, 0, stream>>>(attn_b, xT, e_out);
}